// Round 6
// baseline (41.381 us; speedup 1.0000x reference)
//
#include <hip/hip_runtime.h>
#include <math.h>

// Van Rossum loss, single big dispatch + tiny init dispatch.
//   f[t] = r*f[t-1] + cp*x[t],  x = spike - target
//   loss = mean_b sum_{t,n} f^2
// Segment-summary monoid (zero-init local scan l over a segment of length L):
//   E = l[L-1], B = sum_k r^{k+1} l[k], C = sum_k l[k]^2
// Combine S1 (len L1) ++ S2 (len L2), A(L) = sum_{k=1..L} r^{2k}:
//   C = C1 + C2 + 2*E1*B2 + E1^2*A(L2)
//   B = B1 + r^L1*(B2 + E1*A(L2))
//   E = E2 + r^L2*E1
// Block = (batch b, 4 float4-columns, all 32 chunks of 32 steps): each thread
// scans one (chunk, column); 5-level LDS tree-fold yields the full-T C per
// column => per-block scalar => device atomicAdd + ticket; last block writes out.
// Counters zeroed by a tiny init kernel each call (poison-safe).

#define B_DIM 32
#define T_DIM 1024
#define N_DIM 256
#define NCHUNK 32
#define LCHUNK 32
#define QPB 4                  // float4 columns per block
#define NBLK (B_DIM * (N_DIM / 4 / QPB))   // 32 * 16 = 512 blocks

__global__ __launch_bounds__(64) void vr_init(float* wsAcc, unsigned* wsCnt)
{
    if (threadIdx.x == 0) { wsAcc[0] = 0.f; wsCnt[0] = 0u; }
}

__global__ __launch_bounds__(128) void vr_main(
    const float* __restrict__ spike, const float* __restrict__ target,
    float* __restrict__ wsAcc, unsigned* __restrict__ wsCnt,
    float* __restrict__ out,
    float r, float cp, float p32, float a32, float invB)
{
    int tid = threadIdx.x;
    int qi  = tid & (QPB - 1);      // 0..3  float4-column within block
    int cl  = tid >> 2;             // 0..31 chunk
    int b   = blockIdx.x >> 4;      // 0..31 batch
    int qg  = blockIdx.x & 15;      // 0..15 column group

    size_t base = ((size_t)(b * T_DIM + cl * LCHUNK) * N_DIM)
                + (size_t)((qg * QPB + qi) << 2);
    const float4* sp = reinterpret_cast<const float4*>(spike + base);
    const float4* tg = reinterpret_cast<const float4*>(target + base);

    float4 l  = make_float4(0.f, 0.f, 0.f, 0.f);
    float4 Bs = make_float4(0.f, 0.f, 0.f, 0.f);
    float4 Cs = make_float4(0.f, 0.f, 0.f, 0.f);
    float w = r;
    #pragma unroll 8
    for (int k = 0; k < LCHUNK; ++k) {
        float4 s = sp[k * (N_DIM / 4)];
        float4 t = tg[k * (N_DIM / 4)];
        float xx = s.x - t.x, xy = s.y - t.y, xz = s.z - t.z, xw = s.w - t.w;
        l.x = fmaf(r, l.x, cp * xx);
        l.y = fmaf(r, l.y, cp * xy);
        l.z = fmaf(r, l.z, cp * xz);
        l.w = fmaf(r, l.w, cp * xw);
        Bs.x = fmaf(w, l.x, Bs.x);
        Bs.y = fmaf(w, l.y, Bs.y);
        Bs.z = fmaf(w, l.z, Bs.z);
        Bs.w = fmaf(w, l.w, Bs.w);
        Cs.x = fmaf(l.x, l.x, Cs.x);
        Cs.y = fmaf(l.y, l.y, Cs.y);
        Cs.z = fmaf(l.z, l.z, Cs.z);
        Cs.w = fmaf(l.w, l.w, Cs.w);
        w *= r;
    }

    // padded rows (stride 5 float4) to break 128B-stride bank aliasing
    __shared__ float4 sE[NCHUNK][QPB + 1];
    __shared__ float4 sB[NCHUNK][QPB + 1];
    __shared__ float4 sC[NCHUNK][QPB + 1];
    sE[cl][qi] = l; sB[cl][qi] = Bs; sC[cl][qi] = Cs;
    __syncthreads();

    float p = p32, a = a32;   // r^L, A(L) for current segment length L
    #pragma unroll
    for (int d = 1; d < NCHUNK; d <<= 1) {
        if ((cl & (2 * d - 1)) == 0) {
            float4 E1 = sE[cl][qi],     B1 = sB[cl][qi],     C1 = sC[cl][qi];
            float4 E2 = sE[cl + d][qi], B2 = sB[cl + d][qi], C2 = sC[cl + d][qi];
            float4 Cn, Bn, En;
            Cn.x = C1.x + C2.x + 2.f * E1.x * B2.x + E1.x * E1.x * a;
            Cn.y = C1.y + C2.y + 2.f * E1.y * B2.y + E1.y * E1.y * a;
            Cn.z = C1.z + C2.z + 2.f * E1.z * B2.z + E1.z * E1.z * a;
            Cn.w = C1.w + C2.w + 2.f * E1.w * B2.w + E1.w * E1.w * a;
            Bn.x = B1.x + p * (B2.x + E1.x * a);
            Bn.y = B1.y + p * (B2.y + E1.y * a);
            Bn.z = B1.z + p * (B2.z + E1.z * a);
            Bn.w = B1.w + p * (B2.w + E1.w * a);
            En.x = E2.x + p * E1.x;
            En.y = E2.y + p * E1.y;
            En.z = E2.z + p * E1.z;
            En.w = E2.w + p * E1.w;
            sE[cl][qi] = En; sB[cl][qi] = Bn; sC[cl][qi] = Cn;
        }
        a = a + p * p * a;    // A(2L) = A(L)*(1 + r^{2L})
        p = p * p;            // r^{2L}
        __syncthreads();
    }

    if (tid < QPB) {
        float4 C4 = sC[0][tid];
        float cs = (C4.x + C4.y) + (C4.z + C4.w);
        cs += __shfl_down(cs, 2);
        cs += __shfl_down(cs, 1);
        if (tid == 0) {
            atomicAdd(wsAcc, cs * invB);
            __threadfence();
            unsigned old = atomicAdd(wsCnt, 1u);
            if (old == (unsigned)(NBLK - 1)) {
                out[0] = atomicAdd(wsAcc, 0.0f);   // full total (all adds fenced before tickets)
            }
        }
    }
}

extern "C" void kernel_launch(void* const* d_in, const int* in_sizes, int n_in,
                              void* d_out, int out_size, void* d_ws, size_t ws_size,
                              hipStream_t stream)
{
    (void)in_sizes; (void)n_in; (void)ws_size; (void)out_size;
    const float* spike  = (const float*)d_in[0];
    const float* target = (const float*)d_in[1];
    float* out = (float*)d_out;

    float*    wsAcc = (float*)d_ws;
    unsigned* wsCnt = (unsigned*)((char*)d_ws + sizeof(float));

    const double tau = 20.0, dt = 1.0;
    const double rd = exp(dt / tau);
    const double r2 = rd * rd;
    float r    = (float)rd;
    float cp   = (float)(exp(-(double)(T_DIM - 1) * dt / tau) / tau);
    float p32  = (float)exp((double)LCHUNK * dt / tau);                    // r^32
    float a32  = (float)(r2 * (pow(r2, (double)LCHUNK) - 1.0) / (r2 - 1.0)); // A(32)
    float invB = 1.0f / (float)B_DIM;

    hipLaunchKernelGGL(vr_init, dim3(1), dim3(64), 0, stream, wsAcc, wsCnt);
    hipLaunchKernelGGL(vr_main, dim3(NBLK), dim3(128), 0, stream,
                       spike, target, wsAcc, wsCnt, out, r, cp, p32, a32, invB);
}

// Round 7
// 27.464 us; speedup vs baseline: 1.5067x; 1.5067x over previous
//
#include <hip/hip_runtime.h>
#include <math.h>

// Van Rossum loss, single main dispatch + tiny init.
//   f[t] = r*f[t-1] + cp*x[t],  x = spike - target;  loss = mean_b sum f^2
// Segment monoid (zero-init scan l over segment len L):
//   E = l[L-1], B = sum_k r^{k+1} l[k], C = sum_k l[k]^2
// Combine S1 ++ S2 (lens L, L), A(L) = sum_{k=1..L} r^{2k}:
//   C = C1 + C2 + 2*E1*B2 + E1^2*A ;  B = B1 + r^L*(B2 + E1*A) ;  E = E2 + r^L*E1
// Block = (batch b, group of 8 float4-columns); thread = (chunk cl, column qi).
// Wave loads cover 8 full 128B lines (8 chunks x 128B rows) -- full-line coalescing.
// Cross-chunk combine: 5-level LDS tree fold (all within the block).
// Cross-block: atomicAdd + ticket; last of 256 blocks writes out[0].

#define B_DIM 32
#define T_DIM 1024
#define N_DIM 256
#define NCHUNK 32
#define LCHUNK 32
#define QPB 8                   // float4-columns per block
#define NBLK (B_DIM * (N_DIM / 4 / QPB))   // 32 * 8 = 256 blocks

__global__ __launch_bounds__(64) void vr_init(float* wsAcc, unsigned* wsCnt)
{
    if (threadIdx.x == 0) { wsAcc[0] = 0.f; wsCnt[0] = 0u; }
}

__global__ __launch_bounds__(256) void vr_main(
    const float* __restrict__ spike, const float* __restrict__ target,
    float* __restrict__ wsAcc, unsigned* __restrict__ wsCnt,
    float* __restrict__ out,
    float r, float cp, float p32, float a32, float invB)
{
    int tid = threadIdx.x;
    int qi  = tid & (QPB - 1);      // 0..7 column within group
    int cl  = tid >> 3;             // 0..31 chunk
    int b   = blockIdx.x >> 3;      // 0..31 batch
    int qg  = blockIdx.x & 7;       // 0..7 column group

    size_t base = ((size_t)(b * T_DIM + cl * LCHUNK) * N_DIM)
                + (size_t)((qg * QPB + qi) << 2);
    const float4* sp = reinterpret_cast<const float4*>(spike + base);
    const float4* tg = reinterpret_cast<const float4*>(target + base);

    float4 l  = make_float4(0.f, 0.f, 0.f, 0.f);
    float4 Bs = make_float4(0.f, 0.f, 0.f, 0.f);
    float4 Cs = make_float4(0.f, 0.f, 0.f, 0.f);
    float w = r;
    #pragma unroll 8
    for (int k = 0; k < LCHUNK; ++k) {
        float4 s = sp[k * (N_DIM / 4)];
        float4 t = tg[k * (N_DIM / 4)];
        float xx = s.x - t.x, xy = s.y - t.y, xz = s.z - t.z, xw = s.w - t.w;
        l.x = fmaf(r, l.x, cp * xx);
        l.y = fmaf(r, l.y, cp * xy);
        l.z = fmaf(r, l.z, cp * xz);
        l.w = fmaf(r, l.w, cp * xw);
        Bs.x = fmaf(w, l.x, Bs.x);
        Bs.y = fmaf(w, l.y, Bs.y);
        Bs.z = fmaf(w, l.z, Bs.z);
        Bs.w = fmaf(w, l.w, Bs.w);
        Cs.x = fmaf(l.x, l.x, Cs.x);
        Cs.y = fmaf(l.y, l.y, Cs.y);
        Cs.z = fmaf(l.z, l.z, Cs.z);
        Cs.w = fmaf(l.w, l.w, Cs.w);
        w *= r;
    }

    __shared__ float4 sE[NCHUNK][QPB + 1];
    __shared__ float4 sB[NCHUNK][QPB + 1];
    __shared__ float4 sC[NCHUNK][QPB + 1];
    sE[cl][qi] = l; sB[cl][qi] = Bs; sC[cl][qi] = Cs;
    __syncthreads();

    float p = p32, a = a32;   // r^L, A(L) for current segment length
    #pragma unroll
    for (int d = 1; d < NCHUNK; d <<= 1) {
        if ((cl & (2 * d - 1)) == 0) {
            float4 E1 = sE[cl][qi],     B1 = sB[cl][qi],     C1 = sC[cl][qi];
            float4 E2 = sE[cl + d][qi], B2 = sB[cl + d][qi], C2 = sC[cl + d][qi];
            float4 Cn, Bn, En;
            Cn.x = C1.x + C2.x + 2.f * E1.x * B2.x + E1.x * E1.x * a;
            Cn.y = C1.y + C2.y + 2.f * E1.y * B2.y + E1.y * E1.y * a;
            Cn.z = C1.z + C2.z + 2.f * E1.z * B2.z + E1.z * E1.z * a;
            Cn.w = C1.w + C2.w + 2.f * E1.w * B2.w + E1.w * E1.w * a;
            Bn.x = B1.x + p * (B2.x + E1.x * a);
            Bn.y = B1.y + p * (B2.y + E1.y * a);
            Bn.z = B1.z + p * (B2.z + E1.z * a);
            Bn.w = B1.w + p * (B2.w + E1.w * a);
            En.x = E2.x + p * E1.x;
            En.y = E2.y + p * E1.y;
            En.z = E2.z + p * E1.z;
            En.w = E2.w + p * E1.w;
            sE[cl][qi] = En; sB[cl][qi] = Bn; sC[cl][qi] = Cn;
        }
        a = a + p * p * a;    // A(2L) = A(L)*(1 + r^{2L})
        p = p * p;            // r^{2L}
        __syncthreads();
    }

    if (tid < QPB) {
        float4 C4 = sC[0][tid];
        float cs = (C4.x + C4.y) + (C4.z + C4.w);
        cs += __shfl_down(cs, 4);
        cs += __shfl_down(cs, 2);
        cs += __shfl_down(cs, 1);
        if (tid == 0) {
            atomicAdd(wsAcc, cs * invB);
            __threadfence();
            unsigned old = atomicAdd(wsCnt, 1u);
            if (old == (unsigned)(NBLK - 1)) {
                out[0] = atomicAdd(wsAcc, 0.0f);   // all adds fenced before tickets
            }
        }
    }
}

extern "C" void kernel_launch(void* const* d_in, const int* in_sizes, int n_in,
                              void* d_out, int out_size, void* d_ws, size_t ws_size,
                              hipStream_t stream)
{
    (void)in_sizes; (void)n_in; (void)ws_size; (void)out_size;
    const float* spike  = (const float*)d_in[0];
    const float* target = (const float*)d_in[1];
    float* out = (float*)d_out;

    float*    wsAcc = (float*)d_ws;
    unsigned* wsCnt = (unsigned*)((char*)d_ws + sizeof(float));

    const double tau = 20.0, dt = 1.0;
    const double rd = exp(dt / tau);
    const double r2 = rd * rd;
    float r    = (float)rd;
    float cp   = (float)(exp(-(double)(T_DIM - 1) * dt / tau) / tau);
    float p32  = (float)exp((double)LCHUNK * dt / tau);                      // r^32
    float a32  = (float)(r2 * (pow(r2, (double)LCHUNK) - 1.0) / (r2 - 1.0)); // A(32)
    float invB = 1.0f / (float)B_DIM;

    hipLaunchKernelGGL(vr_init, dim3(1), dim3(64), 0, stream, wsAcc, wsCnt);
    hipLaunchKernelGGL(vr_main, dim3(NBLK), dim3(256), 0, stream,
                       spike, target, wsAcc, wsCnt, out, r, cp, p32, a32, invB);
}

// Round 8
// 22.082 us; speedup vs baseline: 1.8740x; 1.2438x over previous
//
#include <hip/hip_runtime.h>
#include <math.h>

// Van Rossum loss, 2-dispatch: high-occupancy pass1 + R5 pass2.
//   f[t] = r*f[t-1] + cp*x[t],  x = spike - target;  loss = mean_b sum f^2
// Segment monoid (zero-init scan l over segment len L):
//   E = l[L-1], B = sum_k r^{k+1} l[k], C = sum_k l[k]^2
// Combine S1(len L1) ++ S2(len L2), A(L) = sum_{k=1..L} r^{2k}:
//   C = C1 + C2 + 2*E1*B2 + E1^2*A(L2)
//   B = B1 + r^L1*(B2 + E1*A(L2))
//   E = E2 + r^L2*E1
// pass1: 1024 blocks x 256 thr (4 blocks/CU, 16 waves/CU = 4x R5's MLP).
//   wave = one fine chunk (L=8) of one batch; lanes sweep full 1KB rows
//   (identical load pattern to R5, just 4x the waves). LDS monoid fold of the
//   4 fine summaries -> one len-32 macro summary per block; ws layout and
//   pass2 are byte-identical to R5 (2 MiB round trip).
// pass2: 32 blocks x 64 thr, carry F across 32 macro-chunks; atomic+ticket,
//   last block writes out[0]. wsAcc/wsCnt zeroed by pass1 block 0.

#define B_DIM 32
#define T_DIM 1024
#define N_DIM 256
#define LFINE 8                 // fine-chunk scan length
#define WPB 4                   // fine chunks (waves) per block
#define MACRO 32                // macro-chunks per batch (len 32 each)
#define NBLK1 (B_DIM * MACRO)   // 1024 pass1 blocks
#define NQ 64                   // float4 columns

__global__ __launch_bounds__(256) void vr_pass1(
    const float* __restrict__ spike, const float* __restrict__ target,
    float4* __restrict__ wsE, float4* __restrict__ wsB,
    float* __restrict__ wsC, float* __restrict__ wsAcc, unsigned* __restrict__ wsCnt,
    float r, float cp, float p8, float a8, float a16)
{
    int tid = threadIdx.x;
    if (blockIdx.x == 0 && tid == 0) { wsAcc[0] = 0.f; wsCnt[0] = 0u; }

    int q  = tid & 63;              // float4 column
    int w  = tid >> 6;              // wave = fine chunk within macro-chunk
    int b  = blockIdx.x >> 5;       // batch
    int mc = blockIdx.x & 31;       // macro-chunk
    int t0 = (mc * WPB + w) * LFINE;

    size_t base = ((size_t)(b * T_DIM + t0) * N_DIM) + ((size_t)q << 2);
    const float4* sp = reinterpret_cast<const float4*>(spike + base);
    const float4* tg = reinterpret_cast<const float4*>(target + base);

    float4 l  = make_float4(0.f, 0.f, 0.f, 0.f);
    float4 Bs = make_float4(0.f, 0.f, 0.f, 0.f);
    float4 Cs = make_float4(0.f, 0.f, 0.f, 0.f);
    float wr = r;
    #pragma unroll
    for (int k = 0; k < LFINE; ++k) {
        float4 s = sp[k * (N_DIM / 4)];
        float4 t = tg[k * (N_DIM / 4)];
        float xx = s.x - t.x, xy = s.y - t.y, xz = s.z - t.z, xw = s.w - t.w;
        l.x = fmaf(r, l.x, cp * xx);
        l.y = fmaf(r, l.y, cp * xy);
        l.z = fmaf(r, l.z, cp * xz);
        l.w = fmaf(r, l.w, cp * xw);
        Bs.x = fmaf(wr, l.x, Bs.x);
        Bs.y = fmaf(wr, l.y, Bs.y);
        Bs.z = fmaf(wr, l.z, Bs.z);
        Bs.w = fmaf(wr, l.w, Bs.w);
        Cs.x = fmaf(l.x, l.x, Cs.x);
        Cs.y = fmaf(l.y, l.y, Cs.y);
        Cs.z = fmaf(l.z, l.z, Cs.z);
        Cs.w = fmaf(l.w, l.w, Cs.w);
        wr *= r;
    }

    __shared__ float4 sE[WPB][NQ];
    __shared__ float4 sB[WPB][NQ];
    __shared__ float4 sC[WPB][NQ];
    sE[w][q] = l; sB[w][q] = Bs; sC[w][q] = Cs;
    __syncthreads();

    // level 0: combine (0,1)->0 and (2,3)->2, segment lens 8+8 (p8, a8)
    if ((w & 1) == 0) {
        float4 E1 = sE[w][q],     B1 = sB[w][q],     C1 = sC[w][q];
        float4 E2 = sE[w + 1][q], B2 = sB[w + 1][q], C2 = sC[w + 1][q];
        float4 Cn, Bn, En;
        Cn.x = C1.x + C2.x + 2.f * E1.x * B2.x + E1.x * E1.x * a8;
        Cn.y = C1.y + C2.y + 2.f * E1.y * B2.y + E1.y * E1.y * a8;
        Cn.z = C1.z + C2.z + 2.f * E1.z * B2.z + E1.z * E1.z * a8;
        Cn.w = C1.w + C2.w + 2.f * E1.w * B2.w + E1.w * E1.w * a8;
        Bn.x = B1.x + p8 * (B2.x + E1.x * a8);
        Bn.y = B1.y + p8 * (B2.y + E1.y * a8);
        Bn.z = B1.z + p8 * (B2.z + E1.z * a8);
        Bn.w = B1.w + p8 * (B2.w + E1.w * a8);
        En.x = E2.x + p8 * E1.x;
        En.y = E2.y + p8 * E1.y;
        En.z = E2.z + p8 * E1.z;
        En.w = E2.w + p8 * E1.w;
        sE[w][q] = En; sB[w][q] = Bn; sC[w][q] = Cn;
    }
    __syncthreads();

    // level 1: combine (0,2)->final, segment lens 16+16 (p16 = p8^2, a16)
    if (w == 0) {
        float p16 = p8 * p8;
        float4 E1 = sE[0][q], B1 = sB[0][q], C1 = sC[0][q];
        float4 E2 = sE[2][q], B2 = sB[2][q], C2 = sC[2][q];
        float4 Cn, Bn, En;
        Cn.x = C1.x + C2.x + 2.f * E1.x * B2.x + E1.x * E1.x * a16;
        Cn.y = C1.y + C2.y + 2.f * E1.y * B2.y + E1.y * E1.y * a16;
        Cn.z = C1.z + C2.z + 2.f * E1.z * B2.z + E1.z * E1.z * a16;
        Cn.w = C1.w + C2.w + 2.f * E1.w * B2.w + E1.w * E1.w * a16;
        Bn.x = B1.x + p16 * (B2.x + E1.x * a16);
        Bn.y = B1.y + p16 * (B2.y + E1.y * a16);
        Bn.z = B1.z + p16 * (B2.z + E1.z * a16);
        Bn.w = B1.w + p16 * (B2.w + E1.w * a16);
        En.x = E2.x + p16 * E1.x;
        En.y = E2.y + p16 * E1.y;
        En.z = E2.z + p16 * E1.z;
        En.w = E2.w + p16 * E1.w;

        int o = (mc * B_DIM + b) * NQ + q;
        wsE[o] = En;
        wsB[o] = Bn;

        float cs = (Cn.x + Cn.y) + (Cn.z + Cn.w);
        #pragma unroll
        for (int off = 32; off > 0; off >>= 1) cs += __shfl_down(cs, off);
        if (q == 0) wsC[blockIdx.x] = cs;   // blockIdx = b*32 + mc
    }
}

__global__ __launch_bounds__(64) void vr_pass2(
    const float4* __restrict__ wsE, const float4* __restrict__ wsB,
    const float* __restrict__ wsC, float* __restrict__ wsAcc,
    unsigned* __restrict__ wsCnt, float* __restrict__ out,
    float rL, float A, float invB)
{
    int b = blockIdx.x;          // 0..31
    int q = threadIdx.x;         // 0..63

    float4 F = make_float4(0.f, 0.f, 0.f, 0.f);
    float acc = 0.f;
    #pragma unroll 8
    for (int chunk = 0; chunk < MACRO; ++chunk) {
        int o = (chunk * B_DIM + b) * NQ + q;
        float4 E  = wsE[o];
        float4 Bv = wsB[o];
        acc += A * ((F.x * F.x + F.y * F.y) + (F.z * F.z + F.w * F.w))
             + 2.f * ((F.x * Bv.x + F.y * Bv.y) + (F.z * Bv.z + F.w * Bv.w));
        F.x = fmaf(rL, F.x, E.x);
        F.y = fmaf(rL, F.y, E.y);
        F.z = fmaf(rL, F.z, E.z);
        F.w = fmaf(rL, F.w, E.w);
    }
    if (q < MACRO) acc += wsC[b * MACRO + q];

    #pragma unroll
    for (int off = 32; off > 0; off >>= 1) acc += __shfl_down(acc, off);

    if (q == 0) {
        atomicAdd(wsAcc, acc * invB);
        __threadfence();
        unsigned old = atomicAdd(wsCnt, 1u);
        if (old == (unsigned)(B_DIM - 1)) {
            out[0] = atomicAdd(wsAcc, 0.0f);   // all adds fenced before tickets
        }
    }
}

extern "C" void kernel_launch(void* const* d_in, const int* in_sizes, int n_in,
                              void* d_out, int out_size, void* d_ws, size_t ws_size,
                              hipStream_t stream)
{
    (void)in_sizes; (void)n_in; (void)ws_size; (void)out_size;
    const float* spike  = (const float*)d_in[0];
    const float* target = (const float*)d_in[1];
    float* out = (float*)d_out;

    float4*   wsE   = (float4*)d_ws;                               // 1 MiB
    float4*   wsB   = wsE + (size_t)MACRO * B_DIM * NQ;            // 1 MiB
    float*    wsC   = (float*)(wsB + (size_t)MACRO * B_DIM * NQ);  // 1024 floats
    float*    wsAcc = wsC + NBLK1;
    unsigned* wsCnt = (unsigned*)(wsAcc + 1);

    const double tau = 20.0, dt = 1.0;
    const double rd = exp(dt / tau);
    const double r2 = rd * rd;
    const double A8d  = r2 * (pow(r2, 8.0)  - 1.0) / (r2 - 1.0);
    const double A16d = A8d * (1.0 + pow(rd, 16.0));
    const double A32d = A16d * (1.0 + pow(rd, 32.0));

    float r    = (float)rd;
    float cp   = (float)(exp(-(double)(T_DIM - 1) * dt / tau) / tau);
    float p8   = (float)pow(rd, 8.0);
    float a8   = (float)A8d;
    float a16  = (float)A16d;
    float rL   = (float)pow(rd, 32.0);
    float A32  = (float)A32d;
    float invB = 1.0f / (float)B_DIM;

    hipLaunchKernelGGL(vr_pass1, dim3(NBLK1), dim3(256), 0, stream,
                       spike, target, wsE, wsB, wsC, wsAcc, wsCnt,
                       r, cp, p8, a8, a16);
    hipLaunchKernelGGL(vr_pass2, dim3(B_DIM), dim3(64), 0, stream,
                       wsE, wsB, wsC, wsAcc, wsCnt, out, rL, A32, invB);
}